// Round 8
// baseline (332.634 us; speedup 1.0000x reference)
//
#include <hip/hip_runtime.h>
#include <stdint.h>
#include <math.h>

typedef unsigned short u16;
typedef unsigned long long ull;

// Problem constants (B=16, N=M=4096, D=3)
#define NPTS  4096
#define NB    16
#define NRES  12288               // residuals per (batch, direction)
#define NPAIR 32                  // 16 batches x 2 directions
#define G     16                  // grid cells per axis
#define NCELL 4096                // G^3
#define HCEL  0.0625f             // 1/G
#define SSTR  4160                // starts stride (u16 elems, >= 4097)
#define MARGIN 1e-5f
// 0-indexed order-statistic ranks for jnp.quantile(0.15/0.85, linear)
#define RANK_LO 1843u
#define RANK_HI 10443u

__device__ __forceinline__ uint32_t f2key(float f) {
    uint32_t u = __float_as_uint(f);
    return (u & 0x80000000u) ? ~u : (u | 0x80000000u);
}
__device__ __forceinline__ float key2f(uint32_t k) {
    uint32_t u = (k & 0x80000000u) ? (k ^ 0x80000000u) : ~k;
    return __uint_as_float(u);
}

// ---------------------------------------------------------------------------
// Kernel 1: build — counting-sort targets into 16^3 cells. 32 blocks x 1024.
// Zeroes this pd's histg slice; block 0 zeroes the completion counter.
// ---------------------------------------------------------------------------
__global__ __launch_bounds__(1024) void build_kernel(const float* __restrict__ x,
                                                     const float* __restrict__ y,
                                                     float4* __restrict__ arrA,
                                                     u16* __restrict__ starts,
                                                     u16* __restrict__ idx16,
                                                     uint32_t* __restrict__ histg,
                                                     unsigned int* __restrict__ counter) {
    __shared__ uint32_t hist[NCELL];          // 16 KB
    __shared__ uint32_t wpart[16];
    const int pd = blockIdx.x, b = pd >> 1, dir = pd & 1;
    const float* t = (dir == 0 ? y : x) + (size_t)b * NPTS * 3;
    const int tid = threadIdx.x, lane = tid & 63, wv = tid >> 6;

    #pragma unroll
    for (int j = 0; j < 4; ++j) hist[tid * 4 + j] = 0u;
    histg[(size_t)pd * 2048 + tid * 2 + 0] = 0u;
    histg[(size_t)pd * 2048 + tid * 2 + 1] = 0u;
    if (pd == 0 && tid == 0) counter[0] = 0u;
    __syncthreads();

    // phase 1: 4 targets/thread (12 floats = 3 aligned float4 loads)
    float f[12];
    int ci[4];
    {
        const float4* tp = reinterpret_cast<const float4*>(t + (size_t)tid * 12);
        #pragma unroll
        for (int j = 0; j < 3; ++j) {
            const float4 v = tp[j];
            f[j * 4 + 0] = v.x; f[j * 4 + 1] = v.y; f[j * 4 + 2] = v.z; f[j * 4 + 3] = v.w;
        }
        #pragma unroll
        for (int k = 0; k < 4; ++k) {
            const int cx = (int)(f[k * 3 + 0] * 16.f);
            const int cy = (int)(f[k * 3 + 1] * 16.f);
            const int cz = (int)(f[k * 3 + 2] * 16.f);
            ci[k] = (cx * G + cy) * G + cz;
            atomicAdd(&hist[ci[k]], 1u);
        }
    }
    __syncthreads();

    // phase 2: exclusive scan of 4096 bins (4/thread, 16 waves)
    {
        uint32_t loc[4], sum = 0;
        const int base = tid * 4;
        #pragma unroll
        for (int j = 0; j < 4; ++j) { loc[j] = hist[base + j]; sum += loc[j]; }
        uint32_t sc = sum;
        #pragma unroll
        for (int off = 1; off < 64; off <<= 1) {
            const uint32_t u = __shfl_up(sc, off);
            if (lane >= off) sc += u;
        }
        if (lane == 63) wpart[wv] = sc;
        __syncthreads();
        uint32_t wbase = 0;
        #pragma unroll
        for (int k = 0; k < 16; ++k) wbase += (k < wv) ? wpart[k] : 0u;
        uint32_t ex = wbase + sc - sum;
        #pragma unroll
        for (int j = 0; j < 4; ++j) { hist[base + j] = ex; ex += loc[j]; }
    }
    __syncthreads();

    // starts (exclusive prefix; entry [4096] = total)
    for (int i = tid; i <= NCELL; i += 1024)
        starts[(size_t)pd * SSTR + i] = (u16)((i == NCELL) ? NPTS : hist[i]);
    __syncthreads();

    // phase 3: scatter (order within cell arbitrary; ties use idx16)
    #pragma unroll
    for (int k = 0; k < 4; ++k) {
        const float px = f[k * 3 + 0], py = f[k * 3 + 1], pz = f[k * 3 + 2];
        const uint32_t pos = atomicAdd(&hist[ci[k]], 1u);
        const float w = fmaf(pz, pz, fmaf(py, py, px * px));
        arrA[(size_t)pd * NPTS + pos] = make_float4(-2.f * px, -2.f * py, -2.f * pz, w);
        idx16[(size_t)pd * NPTS + pos] = (u16)(tid * 4 + k);
    }
}

// ---------------------------------------------------------------------------
// Kernel 2: grid NN, one WAVE per 4-cell z-group. grid=(256 cols, 32 pds),
// 256 threads = 4 waves. The wave's candidate superset (9 columns x 6 z-cells
// ~54 pts) loads one-candidate-per-lane into registers (cascade run mapping,
// no runtime-indexed arrays) and is reused across the group's ~4 queries.
// Per query: fma distance + 6-step u64 (key|orig|pos) min-reduce (exact
// first-index ties) + inscribed-box guard; rare wave-cooperative shell
// fallback for queries whose NN may lie outside the 3^3 box.
// ---------------------------------------------------------------------------
__global__ __launch_bounds__(256, 4) void query_kernel(const float4* __restrict__ arrA,
                                                       const u16* __restrict__ starts,
                                                       const u16* __restrict__ idx16,
                                                       uint32_t* __restrict__ keys,
                                                       uint32_t* __restrict__ histg,
                                                       double* __restrict__ partials) {
    __shared__ double wredS[4], wredS2[4];
    const int pd = blockIdx.y;
    const int tid = threadIdx.x, lane = tid & 63, w = tid >> 6;
    const int col = blockIdx.x;               // (cx,cy) column
    const int cx = col >> 4, cy = col & 15;

    const float4* __restrict__ tp   = arrA + (size_t)pd * NPTS;
    const u16*    __restrict__ st   = starts + (size_t)pd * SSTR;
    const u16*    __restrict__ ixp  = idx16 + (size_t)pd * NPTS;
    const float4* __restrict__ qpts = arrA + (size_t)(pd ^ 1) * NPTS;
    const u16*    __restrict__ stq  = starts + (size_t)(pd ^ 1) * SSTR;

    const int cbase = col * 16 + w * 4;       // first query cell of this wave
    const int qs0 = stq[cbase + 0], qs1 = stq[cbase + 1], qs2 = stq[cbase + 2],
              qs3 = stq[cbase + 3], qs4 = stq[cbase + 4];

    double s1 = 0.0, s2 = 0.0;

    if (qs4 > qs0) {                          // wave has queries
        const int zlo = max(w * 4 - 1, 0), zhi = min(w * 4 + 4, G - 1);

        // 9 candidate runs (named registers, no arrays)
        #define RUNB(RR, AV, NV)                                          \
            int AV = 0, NV = 0;                                           \
            { const int ix = cx + (RR) / 3 - 1, iy = cy + (RR) % 3 - 1;   \
              if (ix >= 0 && ix <= G - 1 && iy >= 0 && iy <= G - 1) {     \
                  const int cc = (ix * G + iy) * G;                       \
                  AV = st[cc + zlo];                                      \
                  NV = st[cc + zhi + 1] - AV; } }
        RUNB(0, a0, n0) RUNB(1, a1, n1) RUNB(2, a2, n2)
        RUNB(3, a3, n3) RUNB(4, a4, n4) RUNB(5, a5, n5)
        RUNB(6, a6, n6) RUNB(7, a7, n7) RUNB(8, a8, n8)
        #undef RUNB
        const int nc = n0 + n1 + n2 + n3 + n4 + n5 + n6 + n7 + n8;

        // cascade run-mapping: candidate index li -> sorted-array position
        #define MAPPOS(LI, POS)                                           \
            int POS; { int rem = (LI); POS = a0 + rem;                    \
            rem -= n0; POS = (rem >= 0) ? a1 + rem : POS;                 \
            rem -= n1; POS = (rem >= 0) ? a2 + rem : POS;                 \
            rem -= n2; POS = (rem >= 0) ? a3 + rem : POS;                 \
            rem -= n3; POS = (rem >= 0) ? a4 + rem : POS;                 \
            rem -= n4; POS = (rem >= 0) ? a5 + rem : POS;                 \
            rem -= n5; POS = (rem >= 0) ? a6 + rem : POS;                 \
            rem -= n6; POS = (rem >= 0) ? a7 + rem : POS;                 \
            rem -= n7; POS = (rem >= 0) ? a8 + rem : POS;                 \
            POS = min(POS, NPTS - 1); }

        // round 0 candidates -> registers (1 per lane)
        MAPPOS(lane, p0)
        float4 T0 = tp[p0];
        const ull cp0 = ((ull)ixp[p0] << 16) | (uint32_t)p0;
        if (lane >= nc) T0.w = 3.0e38f;       // invalid lane -> huge distance

        // round 1 (nc in (64,128]) kept in registers too
        const bool r2 = (nc > 64);
        float4 T1 = T0;
        ull cp1 = cp0;
        if (r2) {
            MAPPOS(64 + lane, p1)
            T1 = tp[p1];
            cp1 = ((ull)ixp[p1] << 16) | (uint32_t)p1;
            if (64 + lane >= nc) T1.w = 3.0e38f;
        }

        #define SCANF(A_, E_)                                                     \
            for (int p2 = (A_) + lane; p2 < (E_); p2 += 64) {                     \
                const float4 T = tp[p2];                                          \
                const float d = fmaf(qx, T.x, fmaf(qy, T.y, fmaf(qz, T.z, T.w))); \
                const ull cand = ((ull)f2key(d) << 32) |                          \
                                 ((ull)ixp[p2] << 16) | (uint32_t)p2;             \
                pk = (cand < pk) ? cand : pk; }

        #pragma unroll
        for (int k = 0; k < 4; ++k) {
            const int qa = (k == 0) ? qs0 : (k == 1) ? qs1 : (k == 2) ? qs2 : qs3;
            const int qb = (k == 0) ? qs1 : (k == 1) ? qs2 : (k == 2) ? qs3 : qs4;
            const int zc = w * 4 + k;
            for (int qp = qa; qp < qb; ++qp) {
                const float4 Q = qpts[qp];    // wave-uniform -> broadcast
                const float qx = -0.5f * Q.x, qy = -0.5f * Q.y, qz = -0.5f * Q.z;
                const float qq = Q.w;

                const float d0v = fmaf(qx, T0.x, fmaf(qy, T0.y, fmaf(qz, T0.z, T0.w)));
                ull pk = ((ull)f2key(d0v) << 32) | cp0;
                if (r2) {
                    const float d1v = fmaf(qx, T1.x, fmaf(qy, T1.y, fmaf(qz, T1.z, T1.w)));
                    const ull c1 = ((ull)f2key(d1v) << 32) | cp1;
                    pk = (c1 < pk) ? c1 : pk;
                }
                if (nc > 128) {               // ultra-rare
                    for (int li = 128 + lane; li < nc; li += 64) {
                        MAPPOS(li, pe)
                        const float4 T = tp[pe];
                        const float d = fmaf(qx, T.x, fmaf(qy, T.y, fmaf(qz, T.z, T.w)));
                        const ull ce = ((ull)f2key(d) << 32) |
                                       ((ull)ixp[pe] << 16) | (uint32_t)pe;
                        pk = (ce < pk) ? ce : pk;
                    }
                }
                #pragma unroll
                for (int off = 1; off < 64; off <<= 1) {
                    const ull o = __shfl_xor(pk, off);
                    pk = (o < pk) ? o : pk;
                }

                // inscribed-box guard: all unscanned points are >= g away
                const float bd2 = key2f((uint32_t)(pk >> 32)) + qq;
                const float fxm = (cx > 0)     ? qx - (float)(cx - 1) * HCEL : 1e9f;
                const float fxp = (cx < G - 1) ? (float)(cx + 2) * HCEL - qx : 1e9f;
                const float fym = (cy > 0)     ? qy - (float)(cy - 1) * HCEL : 1e9f;
                const float fyp = (cy < G - 1) ? (float)(cy + 2) * HCEL - qy : 1e9f;
                const float fzm = (zc > 0)     ? qz - (float)(zc - 1) * HCEL : 1e9f;
                const float fzp = (zc < G - 1) ? (float)(zc + 2) * HCEL - qz : 1e9f;
                const float g = fminf(fminf(fminf(fxm, fxp), fminf(fym, fyp)),
                                      fminf(fzm, fzp));
                if (bd2 > g * g - MARGIN) {
                    // shell fallback (wave-cooperative), s = 2..15
                    for (int s = 2; s <= G - 1; ++s) {
                        const float bq = key2f((uint32_t)(pk >> 32)) + qq;
                        const float dmin = (float)(s - 1) * HCEL;
                        if (dmin * dmin - bq > MARGIN) break;
                        for (int dx = -s; dx <= s; ++dx) {
                            const int ix = cx + dx;
                            if (ix < 0 || ix > G - 1) continue;
                            const int adx = dx < 0 ? -dx : dx;
                            for (int dy = -s; dy <= s; ++dy) {
                                const int iy = cy + dy;
                                if (iy < 0 || iy > G - 1) continue;
                                const int ady = dy < 0 ? -dy : dy;
                                const int cc = (ix * G + iy) * G;
                                if (max(adx, ady) == s) {
                                    const int zl = max(zc - s, 0), zh = min(zc + s, G - 1);
                                    const int a = st[cc + zl], e = st[cc + zh + 1];
                                    SCANF(a, e)
                                } else {
                                    const int z1 = zc - s;
                                    if (z1 >= 0) { const int a = st[cc + z1], e = st[cc + z1 + 1]; SCANF(a, e) }
                                    const int z2 = zc + s;
                                    if (z2 <= G - 1) { const int a = st[cc + z2], e = st[cc + z2 + 1]; SCANF(a, e) }
                                }
                            }
                        }
                        #pragma unroll
                        for (int off = 1; off < 64; off <<= 1) {
                            const ull o = __shfl_xor(pk, off);
                            pk = (o < pk) ? o : pk;
                        }
                    }
                }

                // residuals (exact: -0.5 * (-2t) == t bitwise)
                const int pos = (int)(pk & 0xFFFFull);
                const float4 T = tp[pos];     // wave-uniform -> broadcast
                const float rx = qx - (-0.5f * T.x);
                const float ry = qy - (-0.5f * T.y);
                const float rz = qz - (-0.5f * T.z);
                if (lane < 3) {
                    const uint32_t kk = (lane == 0) ? f2key(rx)
                                       : (lane == 1) ? f2key(ry) : f2key(rz);
                    keys[(size_t)pd * NRES + (size_t)qp * 3 + lane] = kk;
                    atomicAdd(&histg[(size_t)pd * 2048 + (kk >> 21)], 1u);
                }
                if (lane == 0) {
                    s1 += (double)rx + (double)ry + (double)rz;
                    s2 += (double)rx * rx + (double)ry * ry + (double)rz * rz;
                }
            }
        }
        #undef SCANF
        #undef MAPPOS
    }

    // block-level f64 partials (no atomics): [pd*512 + blk] = s, [+256+blk] = s2
    if (lane == 0) { wredS[w] = s1; wredS2[w] = s2; }
    __syncthreads();
    if (tid == 0) {
        partials[(size_t)pd * 512 + blockIdx.x] =
            wredS[0] + wredS[1] + wredS[2] + wredS[3];
        partials[(size_t)pd * 512 + 256 + blockIdx.x] =
            wredS2[0] + wredS2[1] + wredS2[2] + wredS2[3];
    }
}

// ---------------------------------------------------------------------------
// Kernel 3: robust masked std + fused final reduction (last block writes out).
// 32 blocks x 512 threads; keys in registers; radix levels 2/3 in LDS.
// ---------------------------------------------------------------------------
#define STH 512

__device__ __forceinline__ void scan2048(uint32_t* h, uint32_t* wtmp) {
    const int tid = threadIdx.x, lane = tid & 63, wv = tid >> 6;
    const int i = tid * 4;
    const uint32_t a0 = h[i], a1 = h[i + 1], a2 = h[i + 2], a3 = h[i + 3];
    const uint32_t v = a0 + a1 + a2 + a3;
    uint32_t sc = v;
    #pragma unroll
    for (int off = 1; off < 64; off <<= 1) {
        const uint32_t u = __shfl_up(sc, off);
        if (lane >= off) sc += u;
    }
    if (lane == 63) wtmp[wv] = sc;
    __syncthreads();
    uint32_t base = 0;
    #pragma unroll
    for (int k = 0; k < 8; ++k) base += (k < wv) ? wtmp[k] : 0u;
    const uint32_t ex = base + sc - v;
    h[i] = ex; h[i + 1] = ex + a0; h[i + 2] = ex + a0 + a1; h[i + 3] = ex + a0 + a1 + a2;
    __syncthreads();
}

__device__ __forceinline__ int ubin(const uint32_t* cum, int n, uint32_t r) {
    int lo = 0, hi = n - 1;                    // largest b with cum[b] <= r
    while (lo < hi) {
        const int mid = (lo + hi + 1) >> 1;
        if (cum[mid] <= r) lo = mid; else hi = mid - 1;
    }
    return lo;
}

__global__ __launch_bounds__(512) void sigma_kernel(const uint32_t* __restrict__ keysg,
                                                    const uint32_t* __restrict__ histg,
                                                    const double* __restrict__ partials,
                                                    float* __restrict__ sig,
                                                    unsigned int* __restrict__ counter,
                                                    float* __restrict__ out) {
    __shared__ uint32_t hist[4096];            // 16 KB
    __shared__ uint32_t wtmp[8];
    __shared__ double dred[16];
    __shared__ int ired[16];
    __shared__ uint32_t umin[16];
    __shared__ uint32_t bc[8];
    __shared__ double sS[8];

    const int pair = blockIdx.x;
    const int tid = threadIdx.x, lane = tid & 63, wv = tid >> 6;

    // keys into registers (coalesced)
    uint32_t key[24];
    const uint32_t* kp = keysg + (size_t)pair * NRES;
    #pragma unroll
    for (int e = 0; e < 24; ++e) key[e] = kp[e * STH + tid];

    // full sums: parallel reduce of 256 s-parts (waves 0-3) + 256 s2 (waves 4-7)
    {
        double a = partials[(size_t)pair * 512 + tid];
        #pragma unroll
        for (int off = 32; off; off >>= 1) a += __shfl_down(a, off);
        if (lane == 0) sS[wv] = a;
    }
    __syncthreads();
    const double S = sS[0] + sS[1] + sS[2] + sS[3];
    const double S2 = sS[4] + sS[5] + sS[6] + sS[7];
    const double mu = S / NRES;
    const double var_all = (S2 - S * mu) / (NRES - 1);
    const double sd = sqrt(var_all > 0.0 ? var_all : 0.0);

    // ---- Level 1: load pre-built 11-bit histogram, scan ----
    {
        const uint32_t* hg = histg + (size_t)pair * 2048;
        #pragma unroll
        for (int j = 0; j < 4; ++j) hist[tid * 4 + j] = hg[tid * 4 + j];
    }
    __syncthreads();
    scan2048(hist, wtmp);
    if (tid < 2) {
        const uint32_t r = tid ? RANK_HI : RANK_LO;
        const int bb = ubin(hist, 2048, r);
        bc[tid * 4 + 0] = (uint32_t)bb;
        bc[tid * 4 + 1] = r - hist[bb];
    }
    __syncthreads();

    // ---- Level 2: two concurrent 11-bit histograms ----
    const uint32_t pA1 = bc[0], rA1 = bc[1], pB1 = bc[4], rB1 = bc[5];
    #pragma unroll
    for (int j = 0; j < 8; ++j) hist[tid * 8 + j] = 0u;
    __syncthreads();
    #pragma unroll
    for (int e = 0; e < 24; ++e) {
        const uint32_t k = key[e];
        const uint32_t pfx = k >> 21, bin = (k >> 10) & 2047u;
        if (pfx == pA1) atomicAdd(&hist[bin], 1u);
        if (pfx == pB1) atomicAdd(&hist[2048 + bin], 1u);
    }
    __syncthreads();
    scan2048(hist, wtmp);
    scan2048(hist + 2048, wtmp);
    if (tid < 2) {
        const uint32_t* h = hist + tid * 2048;
        const uint32_t pfx = tid ? pB1 : pA1;
        const uint32_t r = tid ? rB1 : rA1;
        const int bb = ubin(h, 2048, r);
        bc[tid * 4 + 0] = (pfx << 11) | (uint32_t)bb;
        bc[tid * 4 + 1] = r - h[bb];
    }
    __syncthreads();

    // ---- Level 3: two concurrent 10-bit histograms -> exact keys ----
    const uint32_t pA2 = bc[0], rA2 = bc[1], pB2 = bc[4], rB2 = bc[5];
    #pragma unroll
    for (int j = 0; j < 8; ++j) hist[tid * 8 + j] = 0u;
    __syncthreads();
    #pragma unroll
    for (int e = 0; e < 24; ++e) {
        const uint32_t k = key[e];
        if ((k >> 10) == pA2) atomicAdd(&hist[k & 1023u], 1u);
        if ((k >> 10) == pB2) atomicAdd(&hist[2048 + (k & 1023u)], 1u);
    }
    __syncthreads();
    scan2048(hist, wtmp);
    scan2048(hist + 2048, wtmp);
    if (tid < 2) {
        const uint32_t* h = hist + tid * 2048;
        const uint32_t pfx = tid ? pB2 : pA2;
        const uint32_t r = tid ? rB2 : rA2;
        const uint32_t rtot = tid ? RANK_HI : RANK_LO;
        const int bb = ubin(h, 1024, r);
        const uint32_t k0 = (pfx << 10) | (uint32_t)bb;
        const uint32_t abs_le = (rtot - r) + h[bb + 1];
        bc[tid * 4 + 0] = k0;
        bc[tid * 4 + 1] = (abs_le >= rtot + 2u) ? 1u : 0u;   // rank+1 shares key?
    }
    __syncthreads();

    // ---- rank+1 keys: duplicate-covered or min key strictly greater ----
    const uint32_t k0 = bc[0], dup1 = bc[1], k2 = bc[4], dup3 = bc[5];
    uint32_t m1 = 0xFFFFFFFFu, m3 = 0xFFFFFFFFu;
    #pragma unroll
    for (int e = 0; e < 24; ++e) {
        const uint32_t k = key[e];
        if (k > k0 && k < m1) m1 = k;
        if (k > k2 && k < m3) m3 = k;
    }
    {
        uint32_t a = m1, c = m3;
        #pragma unroll
        for (int off = 32; off; off >>= 1) {
            const uint32_t ua = __shfl_down(a, off), uc = __shfl_down(c, off);
            a = (ua < a) ? ua : a; c = (uc < c) ? uc : c;
        }
        if (lane == 0) { umin[wv] = a; umin[8 + wv] = c; }
    }
    __syncthreads();
    uint32_t m1r = 0xFFFFFFFFu, m3r = 0xFFFFFFFFu;
    for (int k = 0; k < 8; ++k) {
        m1r = (umin[k] < m1r) ? umin[k] : m1r;
        m3r = (umin[8 + k] < m3r) ? umin[8 + k] : m3r;
    }
    const uint32_t k1 = dup1 ? k0 : m1r;
    const uint32_t k3 = dup3 ? k2 : m3r;

    // Linear-interpolated quantiles
    const double vl0 = (double)key2f(k0), vl1 = (double)key2f(k1);
    const double vh0 = (double)key2f(k2), vh1 = (double)key2f(k3);
    const double fr_lo = 0.15 * (NRES - 1) - (double)RANK_LO;
    const double fr_hi = 0.85 * (NRES - 1) - (double)RANK_HI;
    const float q_lo = (float)(vl0 + fr_lo * (vl1 - vl0));
    const float q_hi = (float)(vh0 + fr_hi * (vh1 - vh0));

    // Pass B: counts + sums under both predicates
    int cq = 0, cs = 0;
    double sq = 0.0, ss = 0.0;
    #pragma unroll
    for (int e = 0; e < 24; ++e) {
        const float f = key2f(key[e]);
        const bool mq = (f < q_lo) || (f > q_hi);
        const bool ms = fabs((double)f - mu) > sd;
        cq += mq; cs += ms;
        if (mq) sq += f;
        if (ms) ss += f;
    }
    {
        double a = sq, c = ss;
        int ai = cq, ci = cs;
        #pragma unroll
        for (int off = 32; off; off >>= 1) {
            a += __shfl_down(a, off); c += __shfl_down(c, off);
            ai += __shfl_down(ai, off); ci += __shfl_down(ci, off);
        }
        if (lane == 0) { dred[wv] = a; dred[8 + wv] = c; ired[wv] = ai; ired[8 + wv] = ci; }
    }
    __syncthreads();
    double sq_t = 0.0, ss_t = 0.0;
    int cq_t = 0, cs_t = 0;
    for (int k = 0; k < 8; ++k) {
        sq_t += dred[k]; ss_t += dred[8 + k];
        cq_t += ired[k]; cs_t += ired[8 + k];
    }

    int mode;                 // 0 = quantile mask, 1 = simple, 2 = all
    double cnt_sel, sum_sel;
    if (cq_t > 0)      { mode = 0; cnt_sel = cq_t; sum_sel = sq_t; }
    else if (cs_t > 0) { mode = 1; cnt_sel = cs_t; sum_sel = ss_t; }
    else               { mode = 2; cnt_sel = NRES; sum_sel = S; }
    const double mean_w = sum_sel / cnt_sel;
    __syncthreads();

    // Pass C: masked unbiased variance
    double acc = 0.0;
    #pragma unroll
    for (int e = 0; e < 24; ++e) {
        const float f = key2f(key[e]);
        bool w;
        if (mode == 0)      w = (f < q_lo) || (f > q_hi);
        else if (mode == 1) w = fabs((double)f - mu) > sd;
        else                w = true;
        if (w) { const double d = (double)f - mean_w; acc += d * d; }
    }
    {
        double a = acc;
        #pragma unroll
        for (int off = 32; off; off >>= 1) a += __shfl_down(a, off);
        if (lane == 0) dred[wv] = a;
    }
    __syncthreads();
    double acc_t = 0.0;
    for (int k = 0; k < 8; ++k) acc_t += dred[k];

    // fused final: last finishing block reduces sig[] and writes out
    if (tid == 0) {
        const float sv = (float)sqrt(acc_t / (cnt_sel - 1.0));
        __hip_atomic_store(&sig[pair], sv, __ATOMIC_RELEASE, __HIP_MEMORY_SCOPE_AGENT);
        const unsigned prev = __hip_atomic_fetch_add(counter, 1u, __ATOMIC_ACQ_REL,
                                                     __HIP_MEMORY_SCOPE_AGENT);
        if (prev == NPAIR - 1) {
            float m = 0.f;
            for (int i = 0; i < NB; ++i) {
                const float s0 = __hip_atomic_load(&sig[2 * i], __ATOMIC_ACQUIRE,
                                                   __HIP_MEMORY_SCOPE_AGENT);
                const float s1v = __hip_atomic_load(&sig[2 * i + 1], __ATOMIC_ACQUIRE,
                                                    __HIP_MEMORY_SCOPE_AGENT);
                m += fmaxf(s0, s1v);
            }
            out[0] = m / (float)NB;
        }
    }
}

extern "C" void kernel_launch(void* const* d_in, const int* in_sizes, int n_in,
                              void* d_out, int out_size, void* d_ws, size_t ws_size,
                              hipStream_t stream) {
    const float* x = (const float*)d_in[0];
    const float* y = (const float*)d_in[1];
    char* w = (char*)d_ws;
    float4*       arrA     = (float4*)(w);                    // 2 MB
    uint32_t*     keys     = (uint32_t*)(w + 2097152);        // 1.5 MB
    uint32_t*     histg    = (uint32_t*)(w + 3670016);        // 256 KB
    double*       partials = (double*)(w + 3932160);          // 128 KB (32 x 512 f64)
    float*        sig      = (float*)(w + 4063232);           // 128 B
    unsigned int* counter  = (unsigned int*)(w + 4063360);    // 128 B
    u16*          starts   = (u16*)(w + 4063488);             // 260 KB
    u16*          idx16    = (u16*)(w + 4329728);             // 256 KB

    build_kernel<<<NPAIR, 1024, 0, stream>>>(x, y, arrA, starts, idx16, histg, counter);
    query_kernel<<<dim3(256, NPAIR), 256, 0, stream>>>(arrA, starts, idx16,
                                                       keys, histg, partials);
    sigma_kernel<<<NPAIR, STH, 0, stream>>>(keys, histg, partials, sig, counter,
                                            (float*)d_out);
}

// Round 9
// 215.190 us; speedup vs baseline: 1.5458x; 1.5458x over previous
//
#include <hip/hip_runtime.h>
#include <stdint.h>
#include <math.h>

typedef unsigned short u16;
typedef unsigned long long ull;

// Problem constants (B=16, N=M=4096, D=3)
#define NPTS  4096
#define NB    16
#define NRES  12288               // residuals per (batch, direction)
#define NPAIR 32                  // 16 batches x 2 directions
#define G     16                  // grid cells per axis
#define NCELL 4096                // G^3
#define HCEL  0.0625f             // 1/G
#define SSTR  4160                // starts stride (u16 elems, >= 4097)
#define MARGIN 1e-5f
// 0-indexed order-statistic ranks for jnp.quantile(0.15/0.85, linear)
#define RANK_LO 1843u
#define RANK_HI 10443u

__device__ __forceinline__ uint32_t f2key(float f) {
    uint32_t u = __float_as_uint(f);
    return (u & 0x80000000u) ? ~u : (u | 0x80000000u);
}
__device__ __forceinline__ float key2f(uint32_t k) {
    uint32_t u = (k & 0x80000000u) ? (k ^ 0x80000000u) : ~k;
    return __uint_as_float(u);
}

// ---------------------------------------------------------------------------
// Kernel 1: build — counting-sort targets into 16^3 cells. 32 blocks x 1024.
// Zeroes this pd's histg slice + the pair/final counters.
// ---------------------------------------------------------------------------
__global__ __launch_bounds__(1024) void build_kernel(const float* __restrict__ x,
                                                     const float* __restrict__ y,
                                                     float4* __restrict__ arrA,
                                                     u16* __restrict__ starts,
                                                     u16* __restrict__ idx16,
                                                     uint32_t* __restrict__ histg,
                                                     unsigned int* __restrict__ counters) {
    __shared__ uint32_t hist[NCELL];          // 16 KB
    __shared__ uint32_t wpart[16];
    const int pd = blockIdx.x, b = pd >> 1, dir = pd & 1;
    const float* t = (dir == 0 ? y : x) + (size_t)b * NPTS * 3;
    const int tid = threadIdx.x, lane = tid & 63, wv = tid >> 6;

    #pragma unroll
    for (int j = 0; j < 4; ++j) hist[tid * 4 + j] = 0u;
    histg[(size_t)pd * 2048 + tid * 2 + 0] = 0u;
    histg[(size_t)pd * 2048 + tid * 2 + 1] = 0u;
    if (tid == 0) counters[pd] = 0u;
    if (pd == 0 && tid == 1) counters[32] = 0u;
    __syncthreads();

    // phase 1: 4 targets/thread (12 floats = 3 aligned float4 loads)
    float f[12];
    int ci[4];
    {
        const float4* tp = reinterpret_cast<const float4*>(t + (size_t)tid * 12);
        #pragma unroll
        for (int j = 0; j < 3; ++j) {
            const float4 v = tp[j];
            f[j * 4 + 0] = v.x; f[j * 4 + 1] = v.y; f[j * 4 + 2] = v.z; f[j * 4 + 3] = v.w;
        }
        #pragma unroll
        for (int k = 0; k < 4; ++k) {
            const int cx = (int)(f[k * 3 + 0] * 16.f);
            const int cy = (int)(f[k * 3 + 1] * 16.f);
            const int cz = (int)(f[k * 3 + 2] * 16.f);
            ci[k] = (cx * G + cy) * G + cz;
            atomicAdd(&hist[ci[k]], 1u);
        }
    }
    __syncthreads();

    // phase 2: exclusive scan of 4096 bins (4/thread, 16 waves)
    {
        uint32_t loc[4], sum = 0;
        const int base = tid * 4;
        #pragma unroll
        for (int j = 0; j < 4; ++j) { loc[j] = hist[base + j]; sum += loc[j]; }
        uint32_t sc = sum;
        #pragma unroll
        for (int off = 1; off < 64; off <<= 1) {
            const uint32_t u = __shfl_up(sc, off);
            if (lane >= off) sc += u;
        }
        if (lane == 63) wpart[wv] = sc;
        __syncthreads();
        uint32_t wbase = 0;
        #pragma unroll
        for (int k = 0; k < 16; ++k) wbase += (k < wv) ? wpart[k] : 0u;
        uint32_t ex = wbase + sc - sum;
        #pragma unroll
        for (int j = 0; j < 4; ++j) { hist[base + j] = ex; ex += loc[j]; }
    }
    __syncthreads();

    // starts (exclusive prefix; entry [4096] = total)
    for (int i = tid; i <= NCELL; i += 1024)
        starts[(size_t)pd * SSTR + i] = (u16)((i == NCELL) ? NPTS : hist[i]);
    __syncthreads();

    // phase 3: scatter (order within cell arbitrary; ties use idx16)
    #pragma unroll
    for (int k = 0; k < 4; ++k) {
        const float px = f[k * 3 + 0], py = f[k * 3 + 1], pz = f[k * 3 + 2];
        const uint32_t pos = atomicAdd(&hist[ci[k]], 1u);
        const float w = fmaf(pz, pz, fmaf(py, py, px * px));
        arrA[(size_t)pd * NPTS + pos] = make_float4(-2.f * px, -2.f * py, -2.f * pz, w);
        idx16[(size_t)pd * NPTS + pos] = (u16)(tid * 4 + k);
    }
}

// ---- helpers for the fused sigma phase (256 threads) ----
template <int BPT>
__device__ __forceinline__ void scanN(uint32_t* h, uint32_t* wtmp) {
    // exclusive prefix over h[0 .. 256*BPT); 256 threads, 4 waves
    const int tid = threadIdx.x, lane = tid & 63, wv = tid >> 6;
    const int base = tid * BPT;
    uint32_t loc[BPT], sum = 0;
    #pragma unroll
    for (int j = 0; j < BPT; ++j) { loc[j] = h[base + j]; sum += loc[j]; }
    uint32_t sc = sum;
    #pragma unroll
    for (int off = 1; off < 64; off <<= 1) {
        const uint32_t u = __shfl_up(sc, off);
        if (lane >= off) sc += u;
    }
    if (lane == 63) wtmp[wv] = sc;
    __syncthreads();
    uint32_t wb = 0;
    #pragma unroll
    for (int k = 0; k < 4; ++k) wb += (k < wv) ? wtmp[k] : 0u;
    uint32_t ex = wb + sc - sum;
    #pragma unroll
    for (int j = 0; j < BPT; ++j) { h[base + j] = ex; ex += loc[j]; }
    __syncthreads();
}

template <int BPT>
__device__ __forceinline__ void psearch(const uint32_t* h, int n, uint32_t r,
                                        uint32_t total, uint32_t* out3) {
    // unique bin with h[i] <= r < h[i+1] (exclusive-prefix array); O(1) parallel
    const int base = threadIdx.x * BPT;
    #pragma unroll
    for (int j = 0; j < BPT; ++j) {
        const int i = base + j;
        const uint32_t lo = h[i];
        const uint32_t hi = (i + 1 < n) ? h[i + 1] : total;
        if (lo <= r && r < hi) { out3[0] = (uint32_t)i; out3[1] = lo; out3[2] = hi; }
    }
}

// ---------------------------------------------------------------------------
// Kernel 2: fused grid-NN query (round-6 proven quad structure) + per-pair
// robust-sigma (run by the LAST-arriving block of each pair) + final output
// (run by the last pair). grid = (64 qblocks, 32 pds) x 256 threads.
// ---------------------------------------------------------------------------
__global__ __launch_bounds__(256, 4) void query_sigma_kernel(const float4* __restrict__ arrA,
                                                             const u16* __restrict__ starts,
                                                             const u16* __restrict__ idx16,
                                                             uint32_t* __restrict__ keys,
                                                             uint32_t* __restrict__ histg,
                                                             double* __restrict__ partials,
                                                             float* __restrict__ sig,
                                                             unsigned int* __restrict__ counters,
                                                             float* __restrict__ out) {
    __shared__ double wred[8];
    __shared__ uint32_t hist[4096];            // 16 KB (sigma phase)
    __shared__ uint32_t wtmp[4];
    __shared__ uint32_t bc[12];                // psearch slots: A=[0..2], B=[3..5]
    __shared__ double dr[16];
    __shared__ int io[8];
    __shared__ uint32_t um[8];
    __shared__ int lastFlag;

    const int pd = blockIdx.y;
    const int tid = threadIdx.x, lane = tid & 63, wv = tid >> 6;
    const int l4 = tid & 3;
    const int p = blockIdx.x * 64 + (tid >> 2);   // sorted query position

    const float4* __restrict__ tp = arrA + (size_t)pd * NPTS;
    const u16* __restrict__ st = starts + (size_t)pd * SSTR;
    const u16* __restrict__ ixp = idx16 + (size_t)pd * NPTS;

    // =================== query phase (round-6 verbatim) ===================
    const float4 Q = arrA[(size_t)(pd ^ 1) * NPTS + p];
    const float qx = -0.5f * Q.x, qy = -0.5f * Q.y, qz = -0.5f * Q.z;
    const float qq = Q.w;                         // |q|^2 (shell bound only)
    const int cx = (int)(qx * 16.f), cy = (int)(qy * 16.f), cz = (int)(qz * 16.f);

    float best = 3.0e38f;
    ull pk = ~0ull;

    #define SCAN_RUN(A_, E_)                                                        \
        for (int p2 = (A_) + l4; p2 < (E_); p2 += 4) {                              \
            const float4 T = tp[p2];                                                \
            const float d = fmaf(qx, T.x, fmaf(qy, T.y, fmaf(qz, T.z, T.w)));       \
            best = fminf(best, d);                                                  \
            const ull cand = ((ull)f2key(d) << 32) |                                \
                             ((ull)ixp[p2] << 16) | (uint32_t)p2;                   \
            pk = (cand < pk) ? cand : pk;                                           \
        }

    {   // Chebyshev <=1: 9 clamped z-runs (border duplicates harmless)
        const int zlo = max(cz - 1, 0), zhi = min(cz + 1, G - 1);
        int a9[9], e9[9];
        #pragma unroll
        for (int r = 0; r < 9; ++r) {
            const int ix = min(max(cx + (r / 3) - 1, 0), G - 1);
            const int iy = min(max(cy + (r % 3) - 1, 0), G - 1);
            const int c0 = (ix * G + iy) * G;
            a9[r] = st[c0 + zlo];
            e9[r] = st[c0 + zhi + 1];
        }
        #pragma unroll
        for (int r = 0; r < 9; ++r) SCAN_RUN(a9[r], e9[r])
    }

    // expand shells while min possible distance could beat the quad's best
    for (int s = 2; s <= G - 1; ++s) {
        float qb = best;
        qb = fminf(qb, __shfl_xor(qb, 1));
        qb = fminf(qb, __shfl_xor(qb, 2));
        const float dmin = (float)(s - 1) * HCEL;
        if (fmaf(dmin, dmin, -(qb + qq)) > MARGIN) break;
        for (int dx = -s; dx <= s; ++dx) {
            const int ix = cx + dx;
            if (ix < 0 || ix > G - 1) continue;
            const int adx = dx < 0 ? -dx : dx;
            for (int dy = -s; dy <= s; ++dy) {
                const int iy = cy + dy;
                if (iy < 0 || iy > G - 1) continue;
                const int ady = dy < 0 ? -dy : dy;
                const int c0 = (ix * G + iy) * G;
                if (max(adx, ady) == s) {        // full z range
                    const int zl = max(cz - s, 0), zh = min(cz + s, G - 1);
                    const int a = st[c0 + zl], e = st[c0 + zh + 1];
                    SCAN_RUN(a, e)
                } else {                         // only z = cz +/- s
                    const int z1 = cz - s;
                    if (z1 >= 0) { const int a = st[c0 + z1], e = st[c0 + z1 + 1]; SCAN_RUN(a, e) }
                    const int z2 = cz + s;
                    if (z2 <= G - 1) { const int a = st[c0 + z2], e = st[c0 + z2 + 1]; SCAN_RUN(a, e) }
                }
            }
        }
    }
    #undef SCAN_RUN

    // quad min-reduce of packed (key, orig, pos)
    {
        ull o = __shfl_xor(pk, 1); pk = (o < pk) ? o : pk;
        o = __shfl_xor(pk, 2);     pk = (o < pk) ? o : pk;
    }

    // residuals (exact: -0.5 * (-2t) == t bitwise)
    const int pos = (int)(pk & 0xFFFFull);
    const float4 T = tp[pos];
    const float rx = qx - (-0.5f * T.x);
    const float ry = qy - (-0.5f * T.y);
    const float rz = qz - (-0.5f * T.z);

    if (l4 < 3) {
        const uint32_t kk = (l4 == 0) ? f2key(rx) : ((l4 == 1) ? f2key(ry) : f2key(rz));
        keys[(size_t)pd * NRES + (size_t)p * 3 + l4] = kk;
        atomicAdd(&histg[(size_t)pd * 2048 + (kk >> 21)], 1u);
    }

    // f64 partial sums (lane 0 of quad only)
    double s1 = 0.0, s2 = 0.0;
    if (l4 == 0) {
        s1 = (double)rx + (double)ry + (double)rz;
        s2 = (double)rx * rx + (double)ry * ry + (double)rz * rz;
    }
    #pragma unroll
    for (int off = 32; off; off >>= 1) { s1 += __shfl_down(s1, off); s2 += __shfl_down(s2, off); }
    if (lane == 0) { wred[wv] = s1; wred[4 + wv] = s2; }
    __syncthreads();                              // also drains all keys/histg stores
    if (tid == 0) {
        double a = 0.0, c = 0.0;
        for (int k = 0; k < 4; ++k) { a += wred[k]; c += wred[4 + k]; }
        partials[(size_t)pd * 128 + blockIdx.x + 0]  = a;    // s   [0..63]
        partials[(size_t)pd * 128 + 64 + blockIdx.x] = c;    // s2  [64..127]
        __threadfence();
        const unsigned prev = __hip_atomic_fetch_add(&counters[pd], 1u,
                                                     __ATOMIC_ACQ_REL,
                                                     __HIP_MEMORY_SCOPE_AGENT);
        lastFlag = (prev == 63);
    }
    __syncthreads();
    if (!lastFlag) return;

    // =================== sigma phase (last block of this pair) ===================
    const uint32_t* kp = keys + (size_t)pd * NRES;

    // S, S2 from 64+64 partials (waves 0/1)
    {
        double a = (tid < 128) ? partials[(size_t)pd * 128 + tid] : 0.0;
        #pragma unroll
        for (int off = 32; off; off >>= 1) a += __shfl_down(a, off);
        if (lane == 0 && wv < 2) dr[wv] = a;
    }
    __syncthreads();
    const double S = dr[0], S2 = dr[1];
    const double mu = S / NRES;
    const double var_all = (S2 - S * mu) / (NRES - 1);
    const double sd = sqrt(var_all > 0.0 ? var_all : 0.0);

    // ---- Level 1: scan pre-built 11-bit histogram + parallel rank search ----
    {
        const uint32_t* hg = histg + (size_t)pd * 2048;
        #pragma unroll
        for (int j = 0; j < 8; ++j) hist[tid * 8 + j] = hg[tid * 8 + j];
    }
    __syncthreads();
    scanN<8>(hist, wtmp);
    psearch<8>(hist, 2048, RANK_LO, NRES, bc + 0);
    psearch<8>(hist, 2048, RANK_HI, NRES, bc + 3);
    __syncthreads();
    const uint32_t pA1 = bc[0], rA1 = RANK_LO - bc[1], totA1 = bc[2] - bc[1];
    const uint32_t pB1 = bc[3], rB1 = RANK_HI - bc[4], totB1 = bc[5] - bc[4];
    __syncthreads();

    // ---- Level 2: two concurrent 11-bit histograms (streamed keys) ----
    #pragma unroll
    for (int j = 0; j < 16; ++j) hist[tid * 16 + j] = 0u;
    __syncthreads();
    for (int j = 0; j < 48; ++j) {
        const uint32_t k = kp[j * 256 + tid];
        if ((k >> 21) == pA1) atomicAdd(&hist[(k >> 10) & 2047u], 1u);
        if ((k >> 21) == pB1) atomicAdd(&hist[2048 + ((k >> 10) & 2047u)], 1u);
    }
    __syncthreads();
    scanN<8>(hist, wtmp);
    scanN<8>(hist + 2048, wtmp);
    psearch<8>(hist, 2048, rA1, totA1, bc + 0);
    psearch<8>(hist + 2048, 2048, rB1, totB1, bc + 3);
    __syncthreads();
    const uint32_t pA2 = (pA1 << 11) | bc[0], rA2 = rA1 - bc[1], totA2 = bc[2] - bc[1];
    const uint32_t pB2 = (pB1 << 11) | bc[3], rB2 = rB1 - bc[4], totB2 = bc[5] - bc[4];
    __syncthreads();

    // ---- Level 3: two concurrent 10-bit histograms -> exact keys ----
    #pragma unroll
    for (int j = 0; j < 8; ++j) hist[tid * 8 + j] = 0u;
    __syncthreads();
    for (int j = 0; j < 48; ++j) {
        const uint32_t k = kp[j * 256 + tid];
        if ((k >> 10) == pA2) atomicAdd(&hist[k & 1023u], 1u);
        if ((k >> 10) == pB2) atomicAdd(&hist[1024 + (k & 1023u)], 1u);
    }
    __syncthreads();
    scanN<4>(hist, wtmp);
    scanN<4>(hist + 1024, wtmp);
    psearch<4>(hist, 1024, rA2, totA2, bc + 0);
    psearch<4>(hist + 1024, 1024, rB2, totB2, bc + 3);
    __syncthreads();
    const uint32_t k0 = (pA2 << 10) | bc[0];
    const uint32_t k2 = (pB2 << 10) | bc[3];
    const bool dup1 = (bc[2] >= rA2 + 2u);        // rank+1 shares key value?
    const bool dup3 = (bc[5] >= rB2 + 2u);

    // ---- m-pass: min key strictly greater than k0 / k2 ----
    uint32_t m1 = 0xFFFFFFFFu, m3 = 0xFFFFFFFFu;
    for (int j = 0; j < 48; ++j) {
        const uint32_t k = kp[j * 256 + tid];
        if (k > k0 && k < m1) m1 = k;
        if (k > k2 && k < m3) m3 = k;
    }
    {
        uint32_t a = m1, c = m3;
        #pragma unroll
        for (int off = 32; off; off >>= 1) {
            const uint32_t ua = __shfl_down(a, off), uc = __shfl_down(c, off);
            a = (ua < a) ? ua : a; c = (uc < c) ? uc : c;
        }
        if (lane == 0) { um[wv] = a; um[4 + wv] = c; }
    }
    __syncthreads();
    uint32_t m1r = min(min(um[0], um[1]), min(um[2], um[3]));
    uint32_t m3r = min(min(um[4], um[5]), min(um[6], um[7]));
    const uint32_t k1 = dup1 ? k0 : m1r;
    const uint32_t k3 = dup3 ? k2 : m3r;

    // Linear-interpolated quantiles
    const double vl0 = (double)key2f(k0), vl1 = (double)key2f(k1);
    const double vh0 = (double)key2f(k2), vh1 = (double)key2f(k3);
    const double fr_lo = 0.15 * (NRES - 1) - (double)RANK_LO;
    const double fr_hi = 0.85 * (NRES - 1) - (double)RANK_HI;
    const float q_lo = (float)(vl0 + fr_lo * (vl1 - vl0));
    const float q_hi = (float)(vh0 + fr_hi * (vh1 - vh0));

    // ---- B-pass: masked counts + Σf + Σf² under both predicates ----
    int cq = 0, cs = 0;
    double sq = 0.0, ss = 0.0, sqq = 0.0, ssq = 0.0;
    for (int j = 0; j < 48; ++j) {
        const uint32_t k = kp[j * 256 + tid];
        const float f = key2f(k);
        const double fd = (double)f;
        if ((f < q_lo) || (f > q_hi)) { cq++; sq += fd; sqq += fd * fd; }
        if (fabs(fd - mu) > sd)       { cs++; ss += fd; ssq += fd * fd; }
    }
    {
        double a0 = sq, a1 = ss, a2 = sqq, a3 = ssq;
        int b0 = cq, b1 = cs;
        #pragma unroll
        for (int off = 32; off; off >>= 1) {
            a0 += __shfl_down(a0, off); a1 += __shfl_down(a1, off);
            a2 += __shfl_down(a2, off); a3 += __shfl_down(a3, off);
            b0 += __shfl_down(b0, off); b1 += __shfl_down(b1, off);
        }
        if (lane == 0) {
            dr[wv] = a0; dr[4 + wv] = a1; dr[8 + wv] = a2; dr[12 + wv] = a3;
            io[wv] = b0; io[4 + wv] = b1;
        }
    }
    __syncthreads();
    if (tid == 0) {
        const double sq_t  = dr[0] + dr[1] + dr[2] + dr[3];
        const double ss_t  = dr[4] + dr[5] + dr[6] + dr[7];
        const double sqq_t = dr[8] + dr[9] + dr[10] + dr[11];
        const double ssq_t = dr[12] + dr[13] + dr[14] + dr[15];
        const int cq_t = io[0] + io[1] + io[2] + io[3];
        const int cs_t = io[4] + io[5] + io[6] + io[7];

        double cnt, sum, sumsq;
        if (cq_t > 0)      { cnt = cq_t;  sum = sq_t; sumsq = sqq_t; }
        else if (cs_t > 0) { cnt = cs_t;  sum = ss_t; sumsq = ssq_t; }
        else               { cnt = NRES;  sum = S;    sumsq = S2; }
        const double mean_w = sum / cnt;
        const double var = (sumsq - cnt * mean_w * mean_w) / (cnt - 1.0);
        const float sv = (float)sqrt(var > 0.0 ? var : 0.0);

        __hip_atomic_store(&sig[pd], sv, __ATOMIC_RELEASE, __HIP_MEMORY_SCOPE_AGENT);
        const unsigned prev = __hip_atomic_fetch_add(&counters[32], 1u,
                                                     __ATOMIC_ACQ_REL,
                                                     __HIP_MEMORY_SCOPE_AGENT);
        if (prev == NPAIR - 1) {                  // final reduction
            float m = 0.f;
            for (int i = 0; i < NB; ++i) {
                const float s0 = __hip_atomic_load(&sig[2 * i], __ATOMIC_ACQUIRE,
                                                   __HIP_MEMORY_SCOPE_AGENT);
                const float s1v = __hip_atomic_load(&sig[2 * i + 1], __ATOMIC_ACQUIRE,
                                                    __HIP_MEMORY_SCOPE_AGENT);
                m += fmaxf(s0, s1v);
            }
            out[0] = m / (float)NB;
        }
    }
}

extern "C" void kernel_launch(void* const* d_in, const int* in_sizes, int n_in,
                              void* d_out, int out_size, void* d_ws, size_t ws_size,
                              hipStream_t stream) {
    const float* x = (const float*)d_in[0];
    const float* y = (const float*)d_in[1];
    char* w = (char*)d_ws;
    float4*       arrA     = (float4*)(w);                    // 2 MB
    uint32_t*     keys     = (uint32_t*)(w + 2097152);        // 1.5 MB
    uint32_t*     histg    = (uint32_t*)(w + 3670016);        // 256 KB
    double*       partials = (double*)(w + 3932160);          // 32 KB (32 x 128 f64)
    float*        sig      = (float*)(w + 3964928);           // 128 B
    unsigned int* counters = (unsigned int*)(w + 3965056);    // 33 u32 (padded 256 B)
    u16*          starts   = (u16*)(w + 3965312);             // 260 KB
    u16*          idx16    = (u16*)(w + 4231552);             // 256 KB

    build_kernel<<<NPAIR, 1024, 0, stream>>>(x, y, arrA, starts, idx16, histg, counters);
    query_sigma_kernel<<<dim3(64, NPAIR), 256, 0, stream>>>(arrA, starts, idx16,
                                                            keys, histg, partials,
                                                            sig, counters,
                                                            (float*)d_out);
}

// Round 10
// 111.927 us; speedup vs baseline: 2.9719x; 1.9226x over previous
//
#include <hip/hip_runtime.h>
#include <stdint.h>
#include <math.h>

typedef unsigned short u16;
typedef unsigned long long ull;

// Problem constants (B=16, N=M=4096, D=3)
#define NPTS  4096
#define NB    16
#define NRES  12288               // residuals per (batch, direction)
#define NPAIR 32                  // 16 batches x 2 directions
#define G     16                  // grid cells per axis
#define NCELL 4096                // G^3
#define HCEL  0.0625f             // 1/G
#define SSTR  4160                // starts stride (u16 elems, >= 4097)
#define MARGIN 1e-5f
// 0-indexed order-statistic ranks for jnp.quantile(0.15/0.85, linear)
#define RANK_LO 1843u
#define RANK_HI 10443u

__device__ __forceinline__ uint32_t f2key(float f) {
    uint32_t u = __float_as_uint(f);
    return (u & 0x80000000u) ? ~u : (u | 0x80000000u);
}
__device__ __forceinline__ float key2f(uint32_t k) {
    uint32_t u = (k & 0x80000000u) ? (k ^ 0x80000000u) : ~k;
    return __uint_as_float(u);
}

// ---------------------------------------------------------------------------
// Kernel 1: build — counting-sort targets into 16^3 cells. 32 blocks x 1024.
// ---------------------------------------------------------------------------
__global__ __launch_bounds__(1024) void build_kernel(const float* __restrict__ x,
                                                     const float* __restrict__ y,
                                                     float4* __restrict__ arrA,
                                                     u16* __restrict__ starts,
                                                     u16* __restrict__ idx16,
                                                     unsigned int* __restrict__ counters) {
    __shared__ uint32_t hist[NCELL];          // 16 KB
    __shared__ uint32_t wpart[16];
    const int pd = blockIdx.x, b = pd >> 1, dir = pd & 1;
    const float* t = (dir == 0 ? y : x) + (size_t)b * NPTS * 3;
    const int tid = threadIdx.x, lane = tid & 63, wv = tid >> 6;

    #pragma unroll
    for (int j = 0; j < 4; ++j) hist[tid * 4 + j] = 0u;
    if (pd == 0 && tid == 0) counters[0] = 0u;
    __syncthreads();

    // phase 1: 4 targets/thread (12 floats = 3 aligned float4 loads)
    float f[12];
    int ci[4];
    {
        const float4* tp = reinterpret_cast<const float4*>(t + (size_t)tid * 12);
        #pragma unroll
        for (int j = 0; j < 3; ++j) {
            const float4 v = tp[j];
            f[j * 4 + 0] = v.x; f[j * 4 + 1] = v.y; f[j * 4 + 2] = v.z; f[j * 4 + 3] = v.w;
        }
        #pragma unroll
        for (int k = 0; k < 4; ++k) {
            const int cx = (int)(f[k * 3 + 0] * 16.f);
            const int cy = (int)(f[k * 3 + 1] * 16.f);
            const int cz = (int)(f[k * 3 + 2] * 16.f);
            ci[k] = (cx * G + cy) * G + cz;
            atomicAdd(&hist[ci[k]], 1u);
        }
    }
    __syncthreads();

    // phase 2: exclusive scan of 4096 bins (4/thread, 16 waves)
    {
        uint32_t loc[4], sum = 0;
        const int base = tid * 4;
        #pragma unroll
        for (int j = 0; j < 4; ++j) { loc[j] = hist[base + j]; sum += loc[j]; }
        uint32_t sc = sum;
        #pragma unroll
        for (int off = 1; off < 64; off <<= 1) {
            const uint32_t u = __shfl_up(sc, off);
            if (lane >= off) sc += u;
        }
        if (lane == 63) wpart[wv] = sc;
        __syncthreads();
        uint32_t wbase = 0;
        #pragma unroll
        for (int k = 0; k < 16; ++k) wbase += (k < wv) ? wpart[k] : 0u;
        uint32_t ex = wbase + sc - sum;
        #pragma unroll
        for (int j = 0; j < 4; ++j) { hist[base + j] = ex; ex += loc[j]; }
    }
    __syncthreads();

    // starts (exclusive prefix; entry [4096] = total)
    for (int i = tid; i <= NCELL; i += 1024)
        starts[(size_t)pd * SSTR + i] = (u16)((i == NCELL) ? NPTS : hist[i]);
    __syncthreads();

    // phase 3: scatter (order within cell arbitrary; ties use idx16)
    #pragma unroll
    for (int k = 0; k < 4; ++k) {
        const float px = f[k * 3 + 0], py = f[k * 3 + 1], pz = f[k * 3 + 2];
        const uint32_t pos = atomicAdd(&hist[ci[k]], 1u);
        const float w = fmaf(pz, pz, fmaf(py, py, px * px));
        arrA[(size_t)pd * NPTS + pos] = make_float4(-2.f * px, -2.f * py, -2.f * pz, w);
        idx16[(size_t)pd * NPTS + pos] = (u16)(tid * 4 + k);
    }
}

// ---------------------------------------------------------------------------
// Kernel 2: grid NN, 4 lanes per query (round-6 proven structure), but
// 8 blocks/CU (__launch_bounds__(256,8)) and no global histogram atomics.
// grid=(64 qblocks, 32 pairdirs) x 256.
// ---------------------------------------------------------------------------
__global__ __launch_bounds__(256, 8) void query_kernel(const float4* __restrict__ arrA,
                                                       const u16* __restrict__ starts,
                                                       const u16* __restrict__ idx16,
                                                       uint32_t* __restrict__ keys,
                                                       double* __restrict__ partials) {
    __shared__ double wred[8];
    const int pd = blockIdx.y;
    const int tid = threadIdx.x, lane = tid & 63, wv = tid >> 6;
    const int l4 = tid & 3;
    const int p = blockIdx.x * 64 + (tid >> 2);   // sorted query position

    const float4* __restrict__ tp = arrA + (size_t)pd * NPTS;
    const u16* __restrict__ st = starts + (size_t)pd * SSTR;
    const u16* __restrict__ ixp = idx16 + (size_t)pd * NPTS;

    const float4 Q = arrA[(size_t)(pd ^ 1) * NPTS + p];
    const float qx = -0.5f * Q.x, qy = -0.5f * Q.y, qz = -0.5f * Q.z;
    const float qq = Q.w;                         // |q|^2 (shell bound only)
    const int cx = (int)(qx * 16.f), cy = (int)(qy * 16.f), cz = (int)(qz * 16.f);

    float best = 3.0e38f;
    ull pk = ~0ull;

    #define SCAN_RUN(A_, E_)                                                        \
        for (int p2 = (A_) + l4; p2 < (E_); p2 += 4) {                              \
            const float4 T = tp[p2];                                                \
            const float d = fmaf(qx, T.x, fmaf(qy, T.y, fmaf(qz, T.z, T.w)));       \
            best = fminf(best, d);                                                  \
            const ull cand = ((ull)f2key(d) << 32) |                                \
                             ((ull)ixp[p2] << 16) | (uint32_t)p2;                   \
            pk = (cand < pk) ? cand : pk;                                           \
        }

    {   // Chebyshev <=1: 9 clamped z-runs (border duplicates harmless)
        const int zlo = max(cz - 1, 0), zhi = min(cz + 1, G - 1);
        int a9[9], e9[9];
        #pragma unroll
        for (int r = 0; r < 9; ++r) {
            const int ix = min(max(cx + (r / 3) - 1, 0), G - 1);
            const int iy = min(max(cy + (r % 3) - 1, 0), G - 1);
            const int c0 = (ix * G + iy) * G;
            a9[r] = st[c0 + zlo];
            e9[r] = st[c0 + zhi + 1];
        }
        #pragma unroll
        for (int r = 0; r < 9; ++r) SCAN_RUN(a9[r], e9[r])
    }

    // expand shells while min possible distance could beat the quad's best
    for (int s = 2; s <= G - 1; ++s) {
        float qb = best;
        qb = fminf(qb, __shfl_xor(qb, 1));
        qb = fminf(qb, __shfl_xor(qb, 2));
        const float dmin = (float)(s - 1) * HCEL;
        if (fmaf(dmin, dmin, -(qb + qq)) > MARGIN) break;
        for (int dx = -s; dx <= s; ++dx) {
            const int ix = cx + dx;
            if (ix < 0 || ix > G - 1) continue;
            const int adx = dx < 0 ? -dx : dx;
            for (int dy = -s; dy <= s; ++dy) {
                const int iy = cy + dy;
                if (iy < 0 || iy > G - 1) continue;
                const int ady = dy < 0 ? -dy : dy;
                const int c0 = (ix * G + iy) * G;
                if (max(adx, ady) == s) {        // full z range
                    const int zl = max(cz - s, 0), zh = min(cz + s, G - 1);
                    const int a = st[c0 + zl], e = st[c0 + zh + 1];
                    SCAN_RUN(a, e)
                } else {                         // only z = cz +/- s
                    const int z1 = cz - s;
                    if (z1 >= 0) { const int a = st[c0 + z1], e = st[c0 + z1 + 1]; SCAN_RUN(a, e) }
                    const int z2 = cz + s;
                    if (z2 <= G - 1) { const int a = st[c0 + z2], e = st[c0 + z2 + 1]; SCAN_RUN(a, e) }
                }
            }
        }
    }
    #undef SCAN_RUN

    // quad min-reduce of packed (key, orig, pos)
    {
        ull o = __shfl_xor(pk, 1); pk = (o < pk) ? o : pk;
        o = __shfl_xor(pk, 2);     pk = (o < pk) ? o : pk;
    }

    // residuals (exact: -0.5 * (-2t) == t bitwise)
    const int pos = (int)(pk & 0xFFFFull);
    const float4 T = tp[pos];
    const float rx = qx - (-0.5f * T.x);
    const float ry = qy - (-0.5f * T.y);
    const float rz = qz - (-0.5f * T.z);

    if (l4 < 3) {
        const uint32_t kk = (l4 == 0) ? f2key(rx) : ((l4 == 1) ? f2key(ry) : f2key(rz));
        keys[(size_t)pd * NRES + (size_t)p * 3 + l4] = kk;
    }

    // f64 partial sums (lane 0 of quad only)
    double s1 = 0.0, s2 = 0.0;
    if (l4 == 0) {
        s1 = (double)rx + (double)ry + (double)rz;
        s2 = (double)rx * rx + (double)ry * ry + (double)rz * rz;
    }
    #pragma unroll
    for (int off = 32; off; off >>= 1) { s1 += __shfl_down(s1, off); s2 += __shfl_down(s2, off); }
    if (lane == 0) { wred[wv] = s1; wred[4 + wv] = s2; }
    __syncthreads();
    if (tid == 0) {
        double a = 0.0, c = 0.0;
        for (int k = 0; k < 4; ++k) { a += wred[k]; c += wred[4 + k]; }
        partials[(size_t)pd * 128 + blockIdx.x + 0]  = a;    // s   [0..63]
        partials[(size_t)pd * 128 + 64 + blockIdx.x] = c;    // s2  [64..127]
    }
}

// ---- helpers for sigma (1024 threads, 16 waves) ----
template <int BPT>
__device__ __forceinline__ void scanB(uint32_t* h, uint32_t* wtmp) {
    // exclusive prefix over h[0 .. 1024*BPT)
    const int tid = threadIdx.x, lane = tid & 63, wv = tid >> 6;
    const int base = tid * BPT;
    uint32_t loc[BPT], sum = 0;
    #pragma unroll
    for (int j = 0; j < BPT; ++j) { loc[j] = h[base + j]; sum += loc[j]; }
    uint32_t sc = sum;
    #pragma unroll
    for (int off = 1; off < 64; off <<= 1) {
        const uint32_t u = __shfl_up(sc, off);
        if (lane >= off) sc += u;
    }
    if (lane == 63) wtmp[wv] = sc;
    __syncthreads();
    uint32_t wb = 0;
    #pragma unroll
    for (int k = 0; k < 16; ++k) wb += (k < wv) ? wtmp[k] : 0u;
    uint32_t ex = wb + sc - sum;
    #pragma unroll
    for (int j = 0; j < BPT; ++j) { h[base + j] = ex; ex += loc[j]; }
    __syncthreads();
}

template <int BPT>
__device__ __forceinline__ void psearchB(const uint32_t* h, int n, uint32_t r,
                                         uint32_t total, uint32_t* out3) {
    // unique bin with h[i] <= r < h[i+1] (exclusive-prefix array)
    const int base = threadIdx.x * BPT;
    #pragma unroll
    for (int j = 0; j < BPT; ++j) {
        const int i = base + j;
        if (i < n) {
            const uint32_t lo = h[i];
            const uint32_t hi = (i + 1 < n) ? h[i + 1] : total;
            if (lo <= r && r < hi) { out3[0] = (uint32_t)i; out3[1] = lo; out3[2] = hi; }
        }
    }
}

// ---------------------------------------------------------------------------
// Kernel 3: robust masked std + fused final. 32 blocks x 1024 threads.
// Keys in registers (12/thread); L1 hist built locally; parallel rank search;
// one-pass f64 variance. Last pair writes the final output.
// ---------------------------------------------------------------------------
__global__ __launch_bounds__(1024) void sigma_kernel(const uint32_t* __restrict__ keysg,
                                                     const double* __restrict__ partials,
                                                     float* __restrict__ sig,
                                                     unsigned int* __restrict__ counters,
                                                     float* __restrict__ out) {
    __shared__ uint32_t hist[4096];            // 16 KB
    __shared__ uint32_t wtmp[16];
    __shared__ uint32_t bc[12];                // psearch slots: A=[0..2], B=[3..5]
    __shared__ double dr[64];
    __shared__ int io[32];
    __shared__ uint32_t um[32];

    const int pair = blockIdx.x;
    const int tid = threadIdx.x, lane = tid & 63, wv = tid >> 6;

    // keys into registers (coalesced, 12/thread)
    uint32_t key[12];
    const uint32_t* kp = keysg + (size_t)pair * NRES;
    #pragma unroll
    for (int e = 0; e < 12; ++e) key[e] = kp[e * 1024 + tid];

    // S, S2 from 64+64 partials (waves 0/1)
    {
        double a = (tid < 128) ? partials[(size_t)pair * 128 + tid] : 0.0;
        #pragma unroll
        for (int off = 32; off; off >>= 1) a += __shfl_down(a, off);
        if (lane == 0 && wv < 2) dr[wv] = a;
    }
    __syncthreads();
    const double S = dr[0], S2 = dr[1];
    const double mu = S / NRES;
    const double var_all = (S2 - S * mu) / (NRES - 1);
    const double sd = sqrt(var_all > 0.0 ? var_all : 0.0);
    __syncthreads();

    // ---- Level 1: 11-bit histogram from register keys ----
    hist[tid * 2] = 0u; hist[tid * 2 + 1] = 0u;
    __syncthreads();
    #pragma unroll
    for (int e = 0; e < 12; ++e) atomicAdd(&hist[key[e] >> 21], 1u);
    __syncthreads();
    scanB<2>(hist, wtmp);
    psearchB<2>(hist, 2048, RANK_LO, NRES, bc + 0);
    psearchB<2>(hist, 2048, RANK_HI, NRES, bc + 3);
    __syncthreads();
    const uint32_t pA1 = bc[0], rA1 = RANK_LO - bc[1], totA1 = bc[2] - bc[1];
    const uint32_t pB1 = bc[3], rB1 = RANK_HI - bc[4], totB1 = bc[5] - bc[4];
    __syncthreads();

    // ---- Level 2: two concurrent 11-bit histograms ----
    #pragma unroll
    for (int j = 0; j < 4; ++j) hist[tid * 4 + j] = 0u;
    __syncthreads();
    #pragma unroll
    for (int e = 0; e < 12; ++e) {
        const uint32_t k = key[e];
        const uint32_t pfx = k >> 21, bin = (k >> 10) & 2047u;
        if (pfx == pA1) atomicAdd(&hist[bin], 1u);
        if (pfx == pB1) atomicAdd(&hist[2048 + bin], 1u);
    }
    __syncthreads();
    scanB<2>(hist, wtmp);
    scanB<2>(hist + 2048, wtmp);
    psearchB<2>(hist, 2048, rA1, totA1, bc + 0);
    psearchB<2>(hist + 2048, 2048, rB1, totB1, bc + 3);
    __syncthreads();
    const uint32_t pA2 = (pA1 << 11) | bc[0], rA2 = rA1 - bc[1], totA2 = bc[2] - bc[1];
    const uint32_t pB2 = (pB1 << 11) | bc[3], rB2 = rB1 - bc[4], totB2 = bc[5] - bc[4];
    __syncthreads();

    // ---- Level 3: two concurrent 10-bit histograms -> exact keys ----
    hist[tid * 2] = 0u; hist[tid * 2 + 1] = 0u;
    __syncthreads();
    #pragma unroll
    for (int e = 0; e < 12; ++e) {
        const uint32_t k = key[e];
        if ((k >> 10) == pA2) atomicAdd(&hist[k & 1023u], 1u);
        if ((k >> 10) == pB2) atomicAdd(&hist[1024 + (k & 1023u)], 1u);
    }
    __syncthreads();
    scanB<1>(hist, wtmp);
    scanB<1>(hist + 1024, wtmp);
    psearchB<1>(hist, 1024, rA2, totA2, bc + 0);
    psearchB<1>(hist + 1024, 1024, rB2, totB2, bc + 3);
    __syncthreads();
    const uint32_t k0 = (pA2 << 10) | bc[0];
    const uint32_t k2 = (pB2 << 10) | bc[3];
    const bool dup1 = (bc[2] >= rA2 + 2u);        // rank+1 shares key value?
    const bool dup3 = (bc[5] >= rB2 + 2u);

    // ---- m-pass: min key strictly greater than k0 / k2 ----
    uint32_t m1 = 0xFFFFFFFFu, m3 = 0xFFFFFFFFu;
    #pragma unroll
    for (int e = 0; e < 12; ++e) {
        const uint32_t k = key[e];
        if (k > k0 && k < m1) m1 = k;
        if (k > k2 && k < m3) m3 = k;
    }
    {
        uint32_t a = m1, c = m3;
        #pragma unroll
        for (int off = 32; off; off >>= 1) {
            const uint32_t ua = __shfl_down(a, off), uc = __shfl_down(c, off);
            a = (ua < a) ? ua : a; c = (uc < c) ? uc : c;
        }
        if (lane == 0) { um[wv] = a; um[16 + wv] = c; }
    }
    __syncthreads();
    uint32_t m1r = 0xFFFFFFFFu, m3r = 0xFFFFFFFFu;
    for (int k = 0; k < 16; ++k) {
        m1r = (um[k] < m1r) ? um[k] : m1r;
        m3r = (um[16 + k] < m3r) ? um[16 + k] : m3r;
    }
    const uint32_t k1 = dup1 ? k0 : m1r;
    const uint32_t k3 = dup3 ? k2 : m3r;

    // Linear-interpolated quantiles
    const double vl0 = (double)key2f(k0), vl1 = (double)key2f(k1);
    const double vh0 = (double)key2f(k2), vh1 = (double)key2f(k3);
    const double fr_lo = 0.15 * (NRES - 1) - (double)RANK_LO;
    const double fr_hi = 0.85 * (NRES - 1) - (double)RANK_HI;
    const float q_lo = (float)(vl0 + fr_lo * (vl1 - vl0));
    const float q_hi = (float)(vh0 + fr_hi * (vh1 - vh0));

    // ---- B-pass: masked counts + Σf + Σf² under both predicates ----
    int cq = 0, cs = 0;
    double sq = 0.0, ss = 0.0, sqq = 0.0, ssq = 0.0;
    #pragma unroll
    for (int e = 0; e < 12; ++e) {
        const float f = key2f(key[e]);
        const double fd = (double)f;
        if ((f < q_lo) || (f > q_hi)) { cq++; sq += fd; sqq += fd * fd; }
        if (fabs(fd - mu) > sd)       { cs++; ss += fd; ssq += fd * fd; }
    }
    {
        double a0 = sq, a1 = ss, a2 = sqq, a3 = ssq;
        int b0 = cq, b1 = cs;
        #pragma unroll
        for (int off = 32; off; off >>= 1) {
            a0 += __shfl_down(a0, off); a1 += __shfl_down(a1, off);
            a2 += __shfl_down(a2, off); a3 += __shfl_down(a3, off);
            b0 += __shfl_down(b0, off); b1 += __shfl_down(b1, off);
        }
        if (lane == 0) {
            dr[wv] = a0; dr[16 + wv] = a1; dr[32 + wv] = a2; dr[48 + wv] = a3;
            io[wv] = b0; io[16 + wv] = b1;
        }
    }
    __syncthreads();
    if (tid == 0) {
        double sq_t = 0, ss_t = 0, sqq_t = 0, ssq_t = 0;
        int cq_t = 0, cs_t = 0;
        for (int k = 0; k < 16; ++k) {
            sq_t += dr[k]; ss_t += dr[16 + k]; sqq_t += dr[32 + k]; ssq_t += dr[48 + k];
            cq_t += io[k]; cs_t += io[16 + k];
        }
        double cnt, sum, sumsq;
        if (cq_t > 0)      { cnt = cq_t;  sum = sq_t; sumsq = sqq_t; }
        else if (cs_t > 0) { cnt = cs_t;  sum = ss_t; sumsq = ssq_t; }
        else               { cnt = NRES;  sum = S;    sumsq = S2; }
        const double mean_w = sum / cnt;
        const double var = (sumsq - cnt * mean_w * mean_w) / (cnt - 1.0);
        const float sv = (float)sqrt(var > 0.0 ? var : 0.0);

        __hip_atomic_store(&sig[pair], sv, __ATOMIC_RELEASE, __HIP_MEMORY_SCOPE_AGENT);
        const unsigned prev = __hip_atomic_fetch_add(&counters[0], 1u,
                                                     __ATOMIC_ACQ_REL,
                                                     __HIP_MEMORY_SCOPE_AGENT);
        if (prev == NPAIR - 1) {                  // final reduction
            float m = 0.f;
            for (int i = 0; i < NB; ++i) {
                const float s0 = __hip_atomic_load(&sig[2 * i], __ATOMIC_ACQUIRE,
                                                   __HIP_MEMORY_SCOPE_AGENT);
                const float s1v = __hip_atomic_load(&sig[2 * i + 1], __ATOMIC_ACQUIRE,
                                                    __HIP_MEMORY_SCOPE_AGENT);
                m += fmaxf(s0, s1v);
            }
            out[0] = m / (float)NB;
        }
    }
}

extern "C" void kernel_launch(void* const* d_in, const int* in_sizes, int n_in,
                              void* d_out, int out_size, void* d_ws, size_t ws_size,
                              hipStream_t stream) {
    const float* x = (const float*)d_in[0];
    const float* y = (const float*)d_in[1];
    char* w = (char*)d_ws;
    float4*       arrA     = (float4*)(w);                    // 2 MB
    uint32_t*     keys     = (uint32_t*)(w + 2097152);        // 1.5 MB
    double*       partials = (double*)(w + 3670016);          // 32 KB (32 x 128 f64)
    float*        sig      = (float*)(w + 3702784);           // 128 B
    unsigned int* counters = (unsigned int*)(w + 3702912);    // 128 B
    u16*          starts   = (u16*)(w + 3703040);             // 260 KB
    u16*          idx16    = (u16*)(w + 3969280);             // 256 KB

    build_kernel<<<NPAIR, 1024, 0, stream>>>(x, y, arrA, starts, idx16, counters);
    query_kernel<<<dim3(64, NPAIR), 256, 0, stream>>>(arrA, starts, idx16,
                                                      keys, partials);
    sigma_kernel<<<NPAIR, 1024, 0, stream>>>(keys, partials, sig, counters,
                                             (float*)d_out);
}

// Round 11
// 108.985 us; speedup vs baseline: 3.0521x; 1.0270x over previous
//
#include <hip/hip_runtime.h>
#include <stdint.h>
#include <math.h>

typedef unsigned short u16;
typedef unsigned long long ull;

// Problem constants (B=16, N=M=4096, D=3)
#define NPTS  4096
#define NB    16
#define NRES  12288               // residuals per (batch, direction)
#define NPAIR 32                  // 16 batches x 2 directions
#define G     16                  // grid cells per axis
#define NCELL 4096                // G^3
#define HCEL  0.0625f             // 1/G
#define SSTR  4160                // starts stride (u16 elems, >= 4097)
#define MARGIN 1e-5f
// 0-indexed order-statistic ranks for jnp.quantile(0.15/0.85, linear)
#define RANK_LO 1843u
#define RANK_HI 10443u

__device__ __forceinline__ uint32_t f2key(float f) {
    uint32_t u = __float_as_uint(f);
    return (u & 0x80000000u) ? ~u : (u | 0x80000000u);
}
__device__ __forceinline__ float key2f(uint32_t k) {
    uint32_t u = (k & 0x80000000u) ? (k ^ 0x80000000u) : ~k;
    return __uint_as_float(u);
}

// ---------------------------------------------------------------------------
// Kernel 1: build — counting-sort targets into 16^3 cells. 32 blocks x 1024.
// (idx16 removed: query tie-breaks by sorted position now.)
// ---------------------------------------------------------------------------
__global__ __launch_bounds__(1024) void build_kernel(const float* __restrict__ x,
                                                     const float* __restrict__ y,
                                                     float4* __restrict__ arrA,
                                                     u16* __restrict__ starts,
                                                     unsigned int* __restrict__ counters) {
    __shared__ uint32_t hist[NCELL];          // 16 KB
    __shared__ uint32_t wpart[16];
    const int pd = blockIdx.x, b = pd >> 1, dir = pd & 1;
    const float* t = (dir == 0 ? y : x) + (size_t)b * NPTS * 3;
    const int tid = threadIdx.x, lane = tid & 63, wv = tid >> 6;

    #pragma unroll
    for (int j = 0; j < 4; ++j) hist[tid * 4 + j] = 0u;
    if (pd == 0 && tid == 0) counters[0] = 0u;
    __syncthreads();

    // phase 1: 4 targets/thread (12 floats = 3 aligned float4 loads)
    float f[12];
    int ci[4];
    {
        const float4* tp = reinterpret_cast<const float4*>(t + (size_t)tid * 12);
        #pragma unroll
        for (int j = 0; j < 3; ++j) {
            const float4 v = tp[j];
            f[j * 4 + 0] = v.x; f[j * 4 + 1] = v.y; f[j * 4 + 2] = v.z; f[j * 4 + 3] = v.w;
        }
        #pragma unroll
        for (int k = 0; k < 4; ++k) {
            const int cx = (int)(f[k * 3 + 0] * 16.f);
            const int cy = (int)(f[k * 3 + 1] * 16.f);
            const int cz = (int)(f[k * 3 + 2] * 16.f);
            ci[k] = (cx * G + cy) * G + cz;
            atomicAdd(&hist[ci[k]], 1u);
        }
    }
    __syncthreads();

    // phase 2: exclusive scan of 4096 bins (4/thread, 16 waves)
    {
        uint32_t loc[4], sum = 0;
        const int base = tid * 4;
        #pragma unroll
        for (int j = 0; j < 4; ++j) { loc[j] = hist[base + j]; sum += loc[j]; }
        uint32_t sc = sum;
        #pragma unroll
        for (int off = 1; off < 64; off <<= 1) {
            const uint32_t u = __shfl_up(sc, off);
            if (lane >= off) sc += u;
        }
        if (lane == 63) wpart[wv] = sc;
        __syncthreads();
        uint32_t wbase = 0;
        #pragma unroll
        for (int k = 0; k < 16; ++k) wbase += (k < wv) ? wpart[k] : 0u;
        uint32_t ex = wbase + sc - sum;
        #pragma unroll
        for (int j = 0; j < 4; ++j) { hist[base + j] = ex; ex += loc[j]; }
    }
    __syncthreads();

    // starts (exclusive prefix; entry [4096] = total)
    for (int i = tid; i <= NCELL; i += 1024)
        starts[(size_t)pd * SSTR + i] = (u16)((i == NCELL) ? NPTS : hist[i]);
    __syncthreads();

    // phase 3: scatter (order within cell arbitrary)
    #pragma unroll
    for (int k = 0; k < 4; ++k) {
        const float px = f[k * 3 + 0], py = f[k * 3 + 1], pz = f[k * 3 + 2];
        const uint32_t pos = atomicAdd(&hist[ci[k]], 1u);
        const float w = fmaf(pz, pz, fmaf(py, py, px * px));
        arrA[(size_t)pd * NPTS + pos] = make_float4(-2.f * px, -2.f * py, -2.f * pz, w);
    }
}

// ---------------------------------------------------------------------------
// Kernel 2: grid NN, 4 lanes per query. grid=(64 qblocks, 32 pairdirs) x 256,
// 8 blocks/CU. Single flattened quad-strided candidate loop over the 27-cell
// neighborhood (cascade position mapping) -> pipelined loads, no per-run
// loop overhead. Tie-break by sorted position (exact ties are measure-zero).
// ---------------------------------------------------------------------------
__global__ __launch_bounds__(256, 8) void query_kernel(const float4* __restrict__ arrA,
                                                       const u16* __restrict__ starts,
                                                       uint32_t* __restrict__ keys,
                                                       double* __restrict__ partials) {
    __shared__ double wred[8];
    const int pd = blockIdx.y;
    const int tid = threadIdx.x, lane = tid & 63, wv = tid >> 6;
    const int l4 = tid & 3;
    const int p = blockIdx.x * 64 + (tid >> 2);   // sorted query position

    const float4* __restrict__ tp = arrA + (size_t)pd * NPTS;
    const u16* __restrict__ st = starts + (size_t)pd * SSTR;

    const float4 Q = arrA[(size_t)(pd ^ 1) * NPTS + p];
    const float qx = -0.5f * Q.x, qy = -0.5f * Q.y, qz = -0.5f * Q.z;
    const float qq = Q.w;                         // |q|^2 (shell bound only)
    const int cx = (int)(qx * 16.f), cy = (int)(qy * 16.f), cz = (int)(qz * 16.f);

    ull pk = ~0ull;

    {   // 9 clamped z-runs (border duplicates harmless for min)
        const int zlo = max(cz - 1, 0), zhi = min(cz + 1, G - 1);
        #define RUNB(RR, AV, NV)                                                  \
            int AV, NV;                                                           \
            { const int ix = min(max(cx + (RR) / 3 - 1, 0), G - 1);               \
              const int iy = min(max(cy + (RR) % 3 - 1, 0), G - 1);               \
              const int cc = (ix * G + iy) * G;                                   \
              AV = st[cc + zlo];                                                  \
              NV = st[cc + zhi + 1] - AV; }
        RUNB(0, a0, n0) RUNB(1, a1, n1) RUNB(2, a2, n2)
        RUNB(3, a3, n3) RUNB(4, a4, n4) RUNB(5, a5, n5)
        RUNB(6, a6, n6) RUNB(7, a7, n7) RUNB(8, a8, n8)
        #undef RUNB
        const int nc = n0 + n1 + n2 + n3 + n4 + n5 + n6 + n7 + n8;

        // flattened quad-strided candidate loop (cascade run mapping)
        for (int li = l4; li < nc; li += 4) {
            int pos;
            {
                int rem = li; pos = a0 + rem;
                rem -= n0; pos = (rem >= 0) ? a1 + rem : pos;
                rem -= n1; pos = (rem >= 0) ? a2 + rem : pos;
                rem -= n2; pos = (rem >= 0) ? a3 + rem : pos;
                rem -= n3; pos = (rem >= 0) ? a4 + rem : pos;
                rem -= n4; pos = (rem >= 0) ? a5 + rem : pos;
                rem -= n5; pos = (rem >= 0) ? a6 + rem : pos;
                rem -= n6; pos = (rem >= 0) ? a7 + rem : pos;
                rem -= n7; pos = (rem >= 0) ? a8 + rem : pos;
                pos = min(pos, NPTS - 1);
            }
            const float4 T = tp[pos];
            const float d = fmaf(qx, T.x, fmaf(qy, T.y, fmaf(qz, T.z, T.w)));
            const ull cand = ((ull)f2key(d) << 32) | (uint32_t)pos;
            pk = (cand < pk) ? cand : pk;
        }
    }

    // quad min-reduce of packed (key, pos)
    {
        ull o = __shfl_xor(pk, 1); pk = (o < pk) ? o : pk;
        o = __shfl_xor(pk, 2);     pk = (o < pk) ? o : pk;
    }

    // shell expansion while the min possible distance could beat current best
    for (int s = 2; s <= G - 1; ++s) {
        const float bd = key2f((uint32_t)(pk >> 32));   // quad-uniform
        const float dmin = (float)(s - 1) * HCEL;
        if (fmaf(dmin, dmin, -(bd + qq)) > MARGIN) break;
        for (int dx = -s; dx <= s; ++dx) {
            const int ix = cx + dx;
            if (ix < 0 || ix > G - 1) continue;
            const int adx = dx < 0 ? -dx : dx;
            for (int dy = -s; dy <= s; ++dy) {
                const int iy = cy + dy;
                if (iy < 0 || iy > G - 1) continue;
                const int ady = dy < 0 ? -dy : dy;
                const int c0 = (ix * G + iy) * G;
                #define SCANS(A_, E_)                                                 \
                    for (int p2 = (A_) + l4; p2 < (E_); p2 += 4) {                    \
                        const float4 T = tp[p2];                                      \
                        const float d = fmaf(qx, T.x, fmaf(qy, T.y,                   \
                                             fmaf(qz, T.z, T.w)));                    \
                        const ull cand = ((ull)f2key(d) << 32) | (uint32_t)p2;        \
                        pk = (cand < pk) ? cand : pk;                                 \
                    }
                if (max(adx, ady) == s) {        // full z range
                    const int zl = max(cz - s, 0), zh = min(cz + s, G - 1);
                    const int a = st[c0 + zl], e = st[c0 + zh + 1];
                    SCANS(a, e)
                } else {                         // only z = cz +/- s
                    const int z1 = cz - s;
                    if (z1 >= 0) { const int a = st[c0 + z1], e = st[c0 + z1 + 1]; SCANS(a, e) }
                    const int z2 = cz + s;
                    if (z2 <= G - 1) { const int a = st[c0 + z2], e = st[c0 + z2 + 1]; SCANS(a, e) }
                }
                #undef SCANS
            }
        }
        // re-reduce across the quad after each shell
        ull o = __shfl_xor(pk, 1); pk = (o < pk) ? o : pk;
        o = __shfl_xor(pk, 2);     pk = (o < pk) ? o : pk;
    }

    // residuals (exact: -0.5 * (-2t) == t bitwise)
    const int pos = (int)(uint32_t)pk;
    const float4 T = tp[pos];
    const float rx = qx - (-0.5f * T.x);
    const float ry = qy - (-0.5f * T.y);
    const float rz = qz - (-0.5f * T.z);

    if (l4 < 3) {
        const uint32_t kk = (l4 == 0) ? f2key(rx) : ((l4 == 1) ? f2key(ry) : f2key(rz));
        keys[(size_t)pd * NRES + (size_t)p * 3 + l4] = kk;
    }

    // f64 partial sums (lane 0 of quad only)
    double s1 = 0.0, s2 = 0.0;
    if (l4 == 0) {
        s1 = (double)rx + (double)ry + (double)rz;
        s2 = (double)rx * rx + (double)ry * ry + (double)rz * rz;
    }
    #pragma unroll
    for (int off = 32; off; off >>= 1) { s1 += __shfl_down(s1, off); s2 += __shfl_down(s2, off); }
    if (lane == 0) { wred[wv] = s1; wred[4 + wv] = s2; }
    __syncthreads();
    if (tid == 0) {
        double a = 0.0, c = 0.0;
        for (int k = 0; k < 4; ++k) { a += wred[k]; c += wred[4 + k]; }
        partials[(size_t)pd * 128 + blockIdx.x + 0]  = a;    // s   [0..63]
        partials[(size_t)pd * 128 + 64 + blockIdx.x] = c;    // s2  [64..127]
    }
}

// ---- helpers for sigma (1024 threads, 16 waves) ----
template <int BPT>
__device__ __forceinline__ void scanB(uint32_t* h, uint32_t* wtmp) {
    // exclusive prefix over h[0 .. 1024*BPT)
    const int tid = threadIdx.x, lane = tid & 63, wv = tid >> 6;
    const int base = tid * BPT;
    uint32_t loc[BPT], sum = 0;
    #pragma unroll
    for (int j = 0; j < BPT; ++j) { loc[j] = h[base + j]; sum += loc[j]; }
    uint32_t sc = sum;
    #pragma unroll
    for (int off = 1; off < 64; off <<= 1) {
        const uint32_t u = __shfl_up(sc, off);
        if (lane >= off) sc += u;
    }
    if (lane == 63) wtmp[wv] = sc;
    __syncthreads();
    uint32_t wb = 0;
    #pragma unroll
    for (int k = 0; k < 16; ++k) wb += (k < wv) ? wtmp[k] : 0u;
    uint32_t ex = wb + sc - sum;
    #pragma unroll
    for (int j = 0; j < BPT; ++j) { h[base + j] = ex; ex += loc[j]; }
    __syncthreads();
}

template <int BPT>
__device__ __forceinline__ void psearchB(const uint32_t* h, int n, uint32_t r,
                                         uint32_t total, uint32_t* out3) {
    // unique bin with h[i] <= r < h[i+1] (exclusive-prefix array)
    const int base = threadIdx.x * BPT;
    #pragma unroll
    for (int j = 0; j < BPT; ++j) {
        const int i = base + j;
        if (i < n) {
            const uint32_t lo = h[i];
            const uint32_t hi = (i + 1 < n) ? h[i + 1] : total;
            if (lo <= r && r < hi) { out3[0] = (uint32_t)i; out3[1] = lo; out3[2] = hi; }
        }
    }
}

// ---------------------------------------------------------------------------
// Kernel 3: robust masked std + fused final. 32 blocks x 1024 threads.
// ---------------------------------------------------------------------------
__global__ __launch_bounds__(1024) void sigma_kernel(const uint32_t* __restrict__ keysg,
                                                     const double* __restrict__ partials,
                                                     float* __restrict__ sig,
                                                     unsigned int* __restrict__ counters,
                                                     float* __restrict__ out) {
    __shared__ uint32_t hist[4096];            // 16 KB
    __shared__ uint32_t wtmp[16];
    __shared__ uint32_t bc[12];                // psearch slots: A=[0..2], B=[3..5]
    __shared__ double dr[64];
    __shared__ int io[32];
    __shared__ uint32_t um[32];

    const int pair = blockIdx.x;
    const int tid = threadIdx.x, lane = tid & 63, wv = tid >> 6;

    // keys into registers (coalesced, 12/thread)
    uint32_t key[12];
    const uint32_t* kp = keysg + (size_t)pair * NRES;
    #pragma unroll
    for (int e = 0; e < 12; ++e) key[e] = kp[e * 1024 + tid];

    // S, S2 from 64+64 partials (waves 0/1)
    {
        double a = (tid < 128) ? partials[(size_t)pair * 128 + tid] : 0.0;
        #pragma unroll
        for (int off = 32; off; off >>= 1) a += __shfl_down(a, off);
        if (lane == 0 && wv < 2) dr[wv] = a;
    }
    __syncthreads();
    const double S = dr[0], S2 = dr[1];
    const double mu = S / NRES;
    const double var_all = (S2 - S * mu) / (NRES - 1);
    const double sd = sqrt(var_all > 0.0 ? var_all : 0.0);
    __syncthreads();

    // ---- Level 1: 11-bit histogram from register keys ----
    hist[tid * 2] = 0u; hist[tid * 2 + 1] = 0u;
    __syncthreads();
    #pragma unroll
    for (int e = 0; e < 12; ++e) atomicAdd(&hist[key[e] >> 21], 1u);
    __syncthreads();
    scanB<2>(hist, wtmp);
    psearchB<2>(hist, 2048, RANK_LO, NRES, bc + 0);
    psearchB<2>(hist, 2048, RANK_HI, NRES, bc + 3);
    __syncthreads();
    const uint32_t pA1 = bc[0], rA1 = RANK_LO - bc[1], totA1 = bc[2] - bc[1];
    const uint32_t pB1 = bc[3], rB1 = RANK_HI - bc[4], totB1 = bc[5] - bc[4];
    __syncthreads();

    // ---- Level 2: two concurrent 11-bit histograms ----
    #pragma unroll
    for (int j = 0; j < 4; ++j) hist[tid * 4 + j] = 0u;
    __syncthreads();
    #pragma unroll
    for (int e = 0; e < 12; ++e) {
        const uint32_t k = key[e];
        const uint32_t pfx = k >> 21, bin = (k >> 10) & 2047u;
        if (pfx == pA1) atomicAdd(&hist[bin], 1u);
        if (pfx == pB1) atomicAdd(&hist[2048 + bin], 1u);
    }
    __syncthreads();
    scanB<2>(hist, wtmp);
    scanB<2>(hist + 2048, wtmp);
    psearchB<2>(hist, 2048, rA1, totA1, bc + 0);
    psearchB<2>(hist + 2048, 2048, rB1, totB1, bc + 3);
    __syncthreads();
    const uint32_t pA2 = (pA1 << 11) | bc[0], rA2 = rA1 - bc[1], totA2 = bc[2] - bc[1];
    const uint32_t pB2 = (pB1 << 11) | bc[3], rB2 = rB1 - bc[4], totB2 = bc[5] - bc[4];
    __syncthreads();

    // ---- Level 3: two concurrent 10-bit histograms -> exact keys ----
    hist[tid * 2] = 0u; hist[tid * 2 + 1] = 0u;
    __syncthreads();
    #pragma unroll
    for (int e = 0; e < 12; ++e) {
        const uint32_t k = key[e];
        if ((k >> 10) == pA2) atomicAdd(&hist[k & 1023u], 1u);
        if ((k >> 10) == pB2) atomicAdd(&hist[1024 + (k & 1023u)], 1u);
    }
    __syncthreads();
    scanB<1>(hist, wtmp);
    scanB<1>(hist + 1024, wtmp);
    psearchB<1>(hist, 1024, rA2, totA2, bc + 0);
    psearchB<1>(hist + 1024, 1024, rB2, totB2, bc + 3);
    __syncthreads();
    const uint32_t k0 = (pA2 << 10) | bc[0];
    const uint32_t k2 = (pB2 << 10) | bc[3];
    const bool dup1 = (bc[2] >= rA2 + 2u);        // rank+1 shares key value?
    const bool dup3 = (bc[5] >= rB2 + 2u);

    // ---- m-pass: min key strictly greater than k0 / k2 ----
    uint32_t m1 = 0xFFFFFFFFu, m3 = 0xFFFFFFFFu;
    #pragma unroll
    for (int e = 0; e < 12; ++e) {
        const uint32_t k = key[e];
        if (k > k0 && k < m1) m1 = k;
        if (k > k2 && k < m3) m3 = k;
    }
    {
        uint32_t a = m1, c = m3;
        #pragma unroll
        for (int off = 32; off; off >>= 1) {
            const uint32_t ua = __shfl_down(a, off), uc = __shfl_down(c, off);
            a = (ua < a) ? ua : a; c = (uc < c) ? uc : c;
        }
        if (lane == 0) { um[wv] = a; um[16 + wv] = c; }
    }
    __syncthreads();
    uint32_t m1r = 0xFFFFFFFFu, m3r = 0xFFFFFFFFu;
    for (int k = 0; k < 16; ++k) {
        m1r = (um[k] < m1r) ? um[k] : m1r;
        m3r = (um[16 + k] < m3r) ? um[16 + k] : m3r;
    }
    const uint32_t k1 = dup1 ? k0 : m1r;
    const uint32_t k3 = dup3 ? k2 : m3r;

    // Linear-interpolated quantiles
    const double vl0 = (double)key2f(k0), vl1 = (double)key2f(k1);
    const double vh0 = (double)key2f(k2), vh1 = (double)key2f(k3);
    const double fr_lo = 0.15 * (NRES - 1) - (double)RANK_LO;
    const double fr_hi = 0.85 * (NRES - 1) - (double)RANK_HI;
    const float q_lo = (float)(vl0 + fr_lo * (vl1 - vl0));
    const float q_hi = (float)(vh0 + fr_hi * (vh1 - vh0));

    // ---- B-pass: masked counts + Σf + Σf² under both predicates ----
    int cq = 0, cs = 0;
    double sq = 0.0, ss = 0.0, sqq = 0.0, ssq = 0.0;
    #pragma unroll
    for (int e = 0; e < 12; ++e) {
        const float f = key2f(key[e]);
        const double fd = (double)f;
        if ((f < q_lo) || (f > q_hi)) { cq++; sq += fd; sqq += fd * fd; }
        if (fabs(fd - mu) > sd)       { cs++; ss += fd; ssq += fd * fd; }
    }
    {
        double a0 = sq, a1 = ss, a2 = sqq, a3 = ssq;
        int b0 = cq, b1 = cs;
        #pragma unroll
        for (int off = 32; off; off >>= 1) {
            a0 += __shfl_down(a0, off); a1 += __shfl_down(a1, off);
            a2 += __shfl_down(a2, off); a3 += __shfl_down(a3, off);
            b0 += __shfl_down(b0, off); b1 += __shfl_down(b1, off);
        }
        if (lane == 0) {
            dr[wv] = a0; dr[16 + wv] = a1; dr[32 + wv] = a2; dr[48 + wv] = a3;
            io[wv] = b0; io[16 + wv] = b1;
        }
    }
    __syncthreads();
    if (tid == 0) {
        double sq_t = 0, ss_t = 0, sqq_t = 0, ssq_t = 0;
        int cq_t = 0, cs_t = 0;
        for (int k = 0; k < 16; ++k) {
            sq_t += dr[k]; ss_t += dr[16 + k]; sqq_t += dr[32 + k]; ssq_t += dr[48 + k];
            cq_t += io[k]; cs_t += io[16 + k];
        }
        double cnt, sum, sumsq;
        if (cq_t > 0)      { cnt = cq_t;  sum = sq_t; sumsq = sqq_t; }
        else if (cs_t > 0) { cnt = cs_t;  sum = ss_t; sumsq = ssq_t; }
        else               { cnt = NRES;  sum = S;    sumsq = S2; }
        const double mean_w = sum / cnt;
        const double var = (sumsq - cnt * mean_w * mean_w) / (cnt - 1.0);
        const float sv = (float)sqrt(var > 0.0 ? var : 0.0);

        __hip_atomic_store(&sig[pair], sv, __ATOMIC_RELEASE, __HIP_MEMORY_SCOPE_AGENT);
        const unsigned prev = __hip_atomic_fetch_add(&counters[0], 1u,
                                                     __ATOMIC_ACQ_REL,
                                                     __HIP_MEMORY_SCOPE_AGENT);
        if (prev == NPAIR - 1) {                  // final reduction
            float m = 0.f;
            for (int i = 0; i < NB; ++i) {
                const float s0 = __hip_atomic_load(&sig[2 * i], __ATOMIC_ACQUIRE,
                                                   __HIP_MEMORY_SCOPE_AGENT);
                const float s1v = __hip_atomic_load(&sig[2 * i + 1], __ATOMIC_ACQUIRE,
                                                    __HIP_MEMORY_SCOPE_AGENT);
                m += fmaxf(s0, s1v);
            }
            out[0] = m / (float)NB;
        }
    }
}

extern "C" void kernel_launch(void* const* d_in, const int* in_sizes, int n_in,
                              void* d_out, int out_size, void* d_ws, size_t ws_size,
                              hipStream_t stream) {
    const float* x = (const float*)d_in[0];
    const float* y = (const float*)d_in[1];
    char* w = (char*)d_ws;
    float4*       arrA     = (float4*)(w);                    // 2 MB
    uint32_t*     keys     = (uint32_t*)(w + 2097152);        // 1.5 MB
    double*       partials = (double*)(w + 3670016);          // 32 KB (32 x 128 f64)
    float*        sig      = (float*)(w + 3702784);           // 128 B
    unsigned int* counters = (unsigned int*)(w + 3702912);    // 128 B
    u16*          starts   = (u16*)(w + 3703040);             // 260 KB

    build_kernel<<<NPAIR, 1024, 0, stream>>>(x, y, arrA, starts, counters);
    query_kernel<<<dim3(64, NPAIR), 256, 0, stream>>>(arrA, starts, keys, partials);
    sigma_kernel<<<NPAIR, 1024, 0, stream>>>(keys, partials, sig, counters,
                                             (float*)d_out);
}